// Round 17
// baseline (129.582 us; speedup 1.0000x reference)
//
#include <hip/hip_runtime.h>
#include <stdint.h>

typedef short bf16x8 __attribute__((ext_vector_type(8)));
typedef float f32x4 __attribute__((ext_vector_type(4)));

__device__ __forceinline__ unsigned short f2bf(float f) {
  uint32_t u = __float_as_uint(f);
  u = (u + 0x7FFFu + ((u >> 16) & 1u)) >> 16;
  return (unsigned short)u;
}

__device__ __forceinline__ void gload16(const void* g, void* lds) {
  const __attribute__((address_space(1))) char* gp =
      (const __attribute__((address_space(1))) char*)(uintptr_t)g;
  __attribute__((address_space(3))) char* sp =
      (__attribute__((address_space(3))) char*)(uint32_t)(uintptr_t)lds;
  __builtin_amdgcn_global_load_lds(gp, sp, 16, 0, 0);
}

// ---------------- fused fp32 -> bf16 converts (all 5 tensors, one dispatch) ----------------
__global__ void k_cvt_all(const float* __restrict__ x, const float* __restrict__ Wq,
                          const float* __restrict__ Wk, const float* __restrict__ Wv,
                          const float* __restrict__ Wo, unsigned short* __restrict__ xb,
                          unsigned short* __restrict__ Wcat, unsigned short* __restrict__ Wob) {
  int b = blockIdx.x;
  const float* src;
  unsigned short* dst;
  int off;
  if (b < 4096)       { src = x;  dst = xb;                  off = b; }
  else if (b < 8192)  { src = Wq; dst = Wcat;                off = b - 4096; }
  else if (b < 9216)  { src = Wk; dst = Wcat + 2048 * 2048;  off = b - 8192; }
  else if (b < 10240) { src = Wv; dst = Wcat + 2560 * 2048;  off = b - 9216; }
  else                { src = Wo; dst = Wob;                  off = b - 10240; }
  int i = off * 256 + threadIdx.x;
  float4 v = ((const float4*)src)[i];
  ushort4 o;
  o.x = f2bf(v.x); o.y = f2bf(v.y); o.z = f2bf(v.z); o.w = f2bf(v.w);
  ((ushort4*)dst)[i] = o;
}

// ---------------- bf16 GEMM, 64x128 tile (3 blocks/CU), dbuf: C = A B^T ----------------
// ROPE=1 (gemm0): fp32 RoPE epilogue on Q (scaled, exp2-domain fold) and K; V region
// (n0>=2560, tile-uniform at BN=128) written TRANSPOSED to vtout[d][l] (k_vt fused).
template <int OUTF32, int ROPE>
__global__ __launch_bounds__(256) void k_gemm(const unsigned short* __restrict__ A,
                                              const unsigned short* __restrict__ B,
                                              void* __restrict__ Cout,
                                              int M, int N, int K,
                                              const float* __restrict__ scale_p,
                                              unsigned short* __restrict__ vtout) {
  __shared__ unsigned short As[2][64 * 64];    // 8KB each
  __shared__ unsigned short Bs[2][128 * 64];   // 16KB each
  const int tid = threadIdx.x;
  const int w = tid >> 6, lane = tid & 63;
  const int g = lane >> 4, cl = lane & 15;
  const int nTn = N >> 7;
  const int per = gridDim.x >> 3;
  const int bid = (blockIdx.x & 7) * per + (blockIdx.x >> 3);
  const int tm = bid / nTn, tn = bid % nTn;
  const int m0 = tm << 6, n0 = tn << 7;
  const int wm = (w >> 1) << 5, wn = (w & 1) << 6;  // wave: 32 rows x 64 cols
  f32x4 acc[2][4] = {};

  auto stage = [&](int kt, int b) {
#pragma unroll
    for (int it = 0; it < 6; ++it) {
      int cc = tid + it * 256;           // 1536 chunks: A 512 + B 1024
      int isB = cc >= 512;
      int c3 = isB ? (cc - 512) : cc;
      int row = c3 >> 3, kb = (c3 & 7) << 4;
      const unsigned short* base = isB ? (B + (size_t)(n0 + row) * K + kt)
                                       : (A + (size_t)(m0 + row) * K + kt);
      const char* src = (const char*)base + (kb ^ ((row & 7) << 4));
      char* dstl = (char*)(isB ? Bs[b] : As[b]) + c3 * 16;
      gload16(src, dstl);
    }
  };

  stage(0, 0);
  asm volatile("s_waitcnt vmcnt(0)" ::: "memory");
  __syncthreads();
  int buf = 0;

  for (int kt = 0; kt < K; kt += 64) {
    if (kt + 64 < K) stage(kt + 64, buf ^ 1);
#pragma unroll
    for (int ks = 0; ks < 2; ++ks) {
      bf16x8 af[2], bfr[4];
#pragma unroll
      for (int i = 0; i < 2; ++i) {
        int row = wm + i * 16 + cl;
        int kb = ((g << 4) + (ks << 6)) ^ ((row & 7) << 4);
        af[i] = *(const bf16x8*)((const char*)As[buf] + row * 128 + kb);
      }
#pragma unroll
      for (int j = 0; j < 4; ++j) {
        int row = wn + j * 16 + cl;
        int kb = ((g << 4) + (ks << 6)) ^ ((row & 7) << 4);
        bfr[j] = *(const bf16x8*)((const char*)Bs[buf] + row * 128 + kb);
      }
#pragma unroll
      for (int i = 0; i < 2; ++i)
#pragma unroll
        for (int j = 0; j < 4; ++j)
          acc[i][j] = __builtin_amdgcn_mfma_f32_16x16x32_bf16(af[i], bfr[j], acc[i][j], 0, 0, 0);
    }
    asm volatile("s_waitcnt vmcnt(0)" ::: "memory");
    __syncthreads();
    buf ^= 1;
  }

  if (ROPE && n0 >= 2560) {
    // V region: write transposed to VT[d][l], 4 consecutive l per thread (8B stores)
#pragma unroll
    for (int i = 0; i < 2; ++i)
#pragma unroll
      for (int j = 0; j < 4; ++j) {
        int d = n0 - 2560 + wn + j * 16 + cl;
        int l0r = m0 + wm + i * 16 + (g << 2);
        ushort4 o;
        o.x = f2bf(acc[i][j][0]); o.y = f2bf(acc[i][j][1]);
        o.z = f2bf(acc[i][j][2]); o.w = f2bf(acc[i][j][3]);
        *(ushort4*)(vtout + (size_t)d * 2048 + l0r) = o;
      }
    return;
  }

  if (ROPE) {  // Q (scaled by attn_scale*0.125*log2e) or K: half-split RoPE in fp32
    float s0v = scale_p[0] * 0.125f * 1.4426950408889634f;
    float sc = (n0 < 2048) ? s0v : 1.0f;
    float invf[2];
#pragma unroll
    for (int j = 0; j < 2; ++j)
      invf[j] = __expf(-(float)(j * 16 + cl) * 0.2878231366242557f);
#pragma unroll
    for (int i = 0; i < 2; ++i)
#pragma unroll
      for (int r = 0; r < 4; ++r) {
        float pos = (float)(m0 + wm + i * 16 + (g << 2) + r);
#pragma unroll
        for (int j = 0; j < 2; ++j) {
          float ang = pos * invf[j];
          float sn, cs;
          __sincosf(ang, &sn, &cs);
          float t1 = acc[i][j][r], t2 = acc[i][j + 2][r];
          acc[i][j][r] = (t1 * cs - t2 * sn) * sc;
          acc[i][j + 2][r] = (t1 * sn + t2 * cs) * sc;
        }
      }
  }

#pragma unroll
  for (int i = 0; i < 2; ++i)
#pragma unroll
    for (int j = 0; j < 4; ++j)
#pragma unroll
      for (int r = 0; r < 4; ++r) {
        int row = m0 + wm + i * 16 + (g << 2) + r;
        int col = n0 + wn + j * 16 + cl;
        float v = acc[i][j][r];
        if (OUTF32)
          ((float*)Cout)[(size_t)row * N + col] = v;
        else
          ((unsigned short*)Cout)[(size_t)row * N + col] = f2bf(v);
      }
}

// ---------------- Flash attention: max-free softmax, 2 q-subtiles per wave ----------------
// Block = (head h, 64 q rows), 2 waves x 32 q (2 sub-tiles of 16). K/V/P layouts identical
// to R14 (128B rows + XOR swizzle). K/V ds_reads SHARED across the 2 q-subtiles: 8 reads
// feed 16 MFMA in QK and PV. Per-iter fixed costs amortized over 2x scores.
__global__ __launch_bounds__(128) void k_attn(const unsigned short* __restrict__ qkv,
                                              const unsigned short* __restrict__ vt,
                                              unsigned short* __restrict__ ao) {
  __shared__ unsigned short Ks[2][64 * 64];   // 8KB each
  __shared__ unsigned short Vs[2][64 * 64];   // 8KB each
  __shared__ unsigned short Ps[2 * 2 * 16 * 64];  // 2 waves x 2 subtiles x 2KB
  const int tid = threadIdx.x;
  const int w = tid >> 6, lane = tid & 63;
  const int g = lane >> 4, cl = lane & 15;
  const int h = blockIdx.x & 31;
  const int qb = 31 - (blockIdx.x >> 5);  // longest-first
  const int q0 = qb << 6;
  const int hk = h >> 2;
  const int qw = q0 + (w << 5);           // wave's 32 q rows
  const int qg0 = qw + cl, qg1 = qw + 16 + cl;

  const unsigned short* qp0 = qkv + (size_t)qg0 * 3072 + h * 64 + g * 8;
  const unsigned short* qp1 = qkv + (size_t)qg1 * 3072 + h * 64 + g * 8;
  bf16x8 qf[2][2];
  qf[0][0] = *(const bf16x8*)qp0;  qf[0][1] = *(const bf16x8*)(qp0 + 32);
  qf[1][0] = *(const bf16x8*)qp1;  qf[1][1] = *(const bf16x8*)(qp1 + 32);

  float l0 = 0.0f, l1 = 0.0f;
  f32x4 acc[2][4] = {};

  char* myP = (char*)Ps + w * 4096;

  // staging bases: 128 threads x 4 chunks; (tid+128it) keeps tid&7 and row&7 invariant
  const int rr = tid >> 3;
  const int kbb = (tid & 7) << 4;
  const char* kS = (const char*)(qkv + 2048 + hk * 64 + (size_t)rr * 3072) + (kbb ^ ((rr & 7) << 4));
  const char* vS = (const char*)(vt + (size_t)hk * 64 * 2048 + (size_t)rr * 2048) + (kbb ^ ((rr & 7) << 4));

  auto stageK = [&](int ck, int b) {
    size_t off = (size_t)ck * 393216;  // 64 rows * 3072 * 2B
#pragma unroll
    for (int it = 0; it < 4; ++it)
      gload16(kS + off + (size_t)it * 98304, (char*)Ks[b] + (tid + it * 128) * 16);
  };
  auto stageV = [&](int ck, int b) {
    size_t off = (size_t)ck * 128;     // 64 kv elems * 2B
#pragma unroll
    for (int it = 0; it < 4; ++it)
      gload16(vS + off + (size_t)it * 65536, (char*)Vs[b] + (tid + it * 128) * 16);
  };

  stageK(0, 0); stageV(0, 0);
  if (qb >= 1) stageK(1, 1);
  asm volatile("s_waitcnt vmcnt(0)" ::: "memory");
  __syncthreads();

  float svP[2][4][4];
  {
    const char* Kc = (const char*)Ks[0];
    __builtin_amdgcn_s_setprio(1);
#pragma unroll
    for (int t = 0; t < 4; ++t) {
      f32x4 s0 = {}, s1 = {};
#pragma unroll
      for (int ks = 0; ks < 2; ++ks) {
        int row = t * 16 + cl;
        int kb = ((g << 4) + (ks << 6)) ^ ((row & 7) << 4);
        bf16x8 kf = *(const bf16x8*)(Kc + row * 128 + kb);  // shared across both q-subtiles
        s0 = __builtin_amdgcn_mfma_f32_16x16x32_bf16(kf, qf[0][ks], s0, 0, 0, 0);
        s1 = __builtin_amdgcn_mfma_f32_16x16x32_bf16(kf, qf[1][ks], s1, 0, 0, 0);
      }
#pragma unroll
      for (int r = 0; r < 4; ++r) { svP[0][t][r] = s0[r]; svP[1][t][r] = s1[r]; }
    }
    __builtin_amdgcn_s_setprio(0);
  }
  __syncthreads();  // all waves done with Ks[0] before iter-0 stages K(2) into it

  for (int i = 0; i <= qb; ++i) {
    if (i + 2 <= qb) stageK(i + 2, i & 1);
    if (i + 1 <= qb) stageV(i + 1, (i + 1) & 1);

    // QK for tile i+1 (K(i+1) landed: staged >=1 iter ago + prior vmcnt(0))
    float svN[2][4][4];
    if (i < qb) {
      const char* Kc = (const char*)Ks[(i + 1) & 1];
      __builtin_amdgcn_s_setprio(1);
#pragma unroll
      for (int t = 0; t < 4; ++t) {
        f32x4 s0 = {}, s1 = {};
#pragma unroll
        for (int ks = 0; ks < 2; ++ks) {
          int row = t * 16 + cl;
          int kb = ((g << 4) + (ks << 6)) ^ ((row & 7) << 4);
          bf16x8 kf = *(const bf16x8*)(Kc + row * 128 + kb);
          s0 = __builtin_amdgcn_mfma_f32_16x16x32_bf16(kf, qf[0][ks], s0, 0, 0, 0);
          s1 = __builtin_amdgcn_mfma_f32_16x16x32_bf16(kf, qf[1][ks], s1, 0, 0, 0);
        }
#pragma unroll
        for (int r = 0; r < 4; ++r) { svN[0][t][r] = s0[r]; svN[1][t][r] = s1[r]; }
      }
      __builtin_amdgcn_s_setprio(0);
    }

    if (i == qb) {  // diagonal tile: causal mask per q-subtile (exp2(-1e9) -> 0)
      const int kv0 = i << 6;
#pragma unroll
      for (int t = 0; t < 4; ++t)
#pragma unroll
        for (int r = 0; r < 4; ++r) {
          int kvg = kv0 + t * 16 + (g << 2) + r;
          if (kvg > qg0) svP[0][t][r] = -1e9f;
          if (kvg > qg1) svP[1][t][r] = -1e9f;
        }
    }

    // ---- max-free softmax: direct exp2, per-lane l accumulation ----
#pragma unroll
    for (int qt = 0; qt < 2; ++qt) {
      float ps = 0.0f;
#pragma unroll
      for (int t = 0; t < 4; ++t) {
        float e0 = __builtin_exp2f(svP[qt][t][0]);
        float e1 = __builtin_exp2f(svP[qt][t][1]);
        float e2 = __builtin_exp2f(svP[qt][t][2]);
        float e3 = __builtin_exp2f(svP[qt][t][3]);
        ps += (e0 + e1) + (e2 + e3);
        uint32_t d0, d1;
        asm("v_cvt_pk_bf16_f32 %0, %1, %2" : "=v"(d0) : "v"(e0), "v"(e1));
        asm("v_cvt_pk_bf16_f32 %0, %1, %2" : "=v"(d1) : "v"(e2), "v"(e3));
        uint2 dd; dd.x = d0; dd.y = d1;
        int kb = ((t << 5) + (g << 3)) ^ ((cl & 7) << 4);
        *(uint2*)(myP + qt * 2048 + cl * 128 + kb) = dd;
      }
      if (qt == 0) l0 += ps; else l1 += ps;
    }

    // ---- PV: V ds_reads shared across the 2 q-subtiles ----
    {
      const char* Vc = (const char*)Vs[i & 1];
      __builtin_amdgcn_s_setprio(1);
#pragma unroll
      for (int ks = 0; ks < 2; ++ks) {
        int kbp = ((g << 4) + (ks << 6)) ^ ((cl & 7) << 4);
        bf16x8 pf0 = *(const bf16x8*)(myP + cl * 128 + kbp);
        bf16x8 pf1 = *(const bf16x8*)(myP + 2048 + cl * 128 + kbp);
#pragma unroll
        for (int t = 0; t < 4; ++t) {
          int row = t * 16 + cl;
          int kbv = ((g << 4) + (ks << 6)) ^ ((row & 7) << 4);
          bf16x8 vf = *(const bf16x8*)(Vc + row * 128 + kbv);
          acc[0][t] = __builtin_amdgcn_mfma_f32_16x16x32_bf16(pf0, vf, acc[0][t], 0, 0, 0);
          acc[1][t] = __builtin_amdgcn_mfma_f32_16x16x32_bf16(pf1, vf, acc[1][t], 0, 0, 0);
        }
      }
      __builtin_amdgcn_s_setprio(0);
    }

    if (i < qb) {
      asm volatile("s_waitcnt vmcnt(0)" ::: "memory");
      __syncthreads();
#pragma unroll
      for (int qt = 0; qt < 2; ++qt)
#pragma unroll
        for (int t = 0; t < 4; ++t)
#pragma unroll
          for (int r = 0; r < 4; ++r) svP[qt][t][r] = svN[qt][t][r];
    }
  }

  // end-of-block l reductions (per q-subtile)
  l0 += __shfl_xor(l0, 16);
  l0 += __shfl_xor(l0, 32);
  l1 += __shfl_xor(l1, 16);
  l1 += __shfl_xor(l1, 32);
#pragma unroll
  for (int qt = 0; qt < 2; ++qt) {
    float lsrc = qt ? l1 : l0;
    float li[4];
#pragma unroll
    for (int r = 0; r < 4; ++r) li[r] = 1.0f / __shfl(lsrc, (g << 2) + r);
#pragma unroll
    for (int t = 0; t < 4; ++t)
#pragma unroll
      for (int r = 0; r < 4; ++r) {
        int row = qw + qt * 16 + (g << 2) + r;
        int col = h * 64 + t * 16 + cl;
        ao[(size_t)row * 2048 + col] = f2bf(acc[qt][t][r] * li[r]);
      }
  }
}

extern "C" void kernel_launch(void* const* d_in, const int* in_sizes, int n_in,
                              void* d_out, int out_size, void* d_ws, size_t ws_size,
                              hipStream_t stream) {
  (void)in_sizes; (void)n_in; (void)out_size; (void)ws_size;
  const float* x  = (const float*)d_in[0];
  const float* sc = (const float*)d_in[1];
  // d_in[2] = mask (causal, applied analytically)
  const float* Wq = (const float*)d_in[3];
  const float* Wk = (const float*)d_in[4];
  const float* Wv = (const float*)d_in[5];
  const float* Wo = (const float*)d_in[6];
  float* out = (float*)d_out;
  char* ws = (char*)d_ws;
  unsigned short* xb   = (unsigned short*)(ws);              // 8 MB
  unsigned short* Wcat = (unsigned short*)(ws + 8388608);    // 12 MB  [3072][2048]
  unsigned short* Wob  = (unsigned short*)(ws + 20971520);   // 8 MB
  unsigned short* QKV  = (unsigned short*)(ws + 29360128);   // 12 MB  [2048][3072] (V third unused)
  unsigned short* VT   = (unsigned short*)(ws + 41943040);   // 2 MB   [8][64][2048]
  unsigned short* AO   = (unsigned short*)(ws + 44040192);   // 8 MB   [2048][2048]

  k_cvt_all<<<14336, 256, 0, stream>>>(x, Wq, Wk, Wv, Wo, xb, Wcat, Wob);
  k_gemm<0, 1><<<768, 256, 0, stream>>>(xb, Wcat, QKV, 2048, 3072, 2048, sc, VT);  // RoPE + V->VT
  k_attn<<<1024, 128, 0, stream>>>(QKV, VT, AO);
  k_gemm<1, 0><<<512, 256, 0, stream>>>(AO, Wob, out, 2048, 2048, 2048, nullptr, nullptr);
}

// Round 18
// 116.105 us; speedup vs baseline: 1.1161x; 1.1161x over previous
//
#include <hip/hip_runtime.h>
#include <stdint.h>

typedef short bf16x8 __attribute__((ext_vector_type(8)));
typedef float f32x4 __attribute__((ext_vector_type(4)));

__device__ __forceinline__ unsigned short f2bf(float f) {
  uint32_t u = __float_as_uint(f);
  u = (u + 0x7FFFu + ((u >> 16) & 1u)) >> 16;
  return (unsigned short)u;
}

__device__ __forceinline__ void gload16(const void* g, void* lds) {
  const __attribute__((address_space(1))) char* gp =
      (const __attribute__((address_space(1))) char*)(uintptr_t)g;
  __attribute__((address_space(3))) char* sp =
      (__attribute__((address_space(3))) char*)(uint32_t)(uintptr_t)lds;
  __builtin_amdgcn_global_load_lds(gp, sp, 16, 0, 0);
}

// ---------------- fused fp32 -> bf16 converts (all 5 tensors, one dispatch) ----------------
__global__ void k_cvt_all(const float* __restrict__ x, const float* __restrict__ Wq,
                          const float* __restrict__ Wk, const float* __restrict__ Wv,
                          const float* __restrict__ Wo, unsigned short* __restrict__ xb,
                          unsigned short* __restrict__ Wcat, unsigned short* __restrict__ Wob) {
  int b = blockIdx.x;
  const float* src;
  unsigned short* dst;
  int off;
  if (b < 4096)       { src = x;  dst = xb;                  off = b; }
  else if (b < 8192)  { src = Wq; dst = Wcat;                off = b - 4096; }
  else if (b < 9216)  { src = Wk; dst = Wcat + 2048 * 2048;  off = b - 8192; }
  else if (b < 10240) { src = Wv; dst = Wcat + 2560 * 2048;  off = b - 9216; }
  else                { src = Wo; dst = Wob;                  off = b - 10240; }
  int i = off * 256 + threadIdx.x;
  float4 v = ((const float4*)src)[i];
  ushort4 o;
  o.x = f2bf(v.x); o.y = f2bf(v.y); o.z = f2bf(v.z); o.w = f2bf(v.w);
  ((ushort4*)dst)[i] = o;
}

// ---------------- bf16 GEMM, 64x128 tile (3 blocks/CU), dbuf: C = A B^T ----------------
// ROPE=1 (gemm0): fp32 RoPE epilogue on Q (scaled, exp2-domain fold) and K; V region
// (n0>=2560, tile-uniform at BN=128) written TRANSPOSED to vtout[d][l] (k_vt fused).
template <int OUTF32, int ROPE>
__global__ __launch_bounds__(256) void k_gemm(const unsigned short* __restrict__ A,
                                              const unsigned short* __restrict__ B,
                                              void* __restrict__ Cout,
                                              int M, int N, int K,
                                              const float* __restrict__ scale_p,
                                              unsigned short* __restrict__ vtout) {
  __shared__ unsigned short As[2][64 * 64];    // 8KB each
  __shared__ unsigned short Bs[2][128 * 64];   // 16KB each
  const int tid = threadIdx.x;
  const int w = tid >> 6, lane = tid & 63;
  const int g = lane >> 4, cl = lane & 15;
  const int nTn = N >> 7;
  const int per = gridDim.x >> 3;
  const int bid = (blockIdx.x & 7) * per + (blockIdx.x >> 3);
  const int tm = bid / nTn, tn = bid % nTn;
  const int m0 = tm << 6, n0 = tn << 7;
  const int wm = (w >> 1) << 5, wn = (w & 1) << 6;  // wave: 32 rows x 64 cols
  f32x4 acc[2][4] = {};

  auto stage = [&](int kt, int b) {
#pragma unroll
    for (int it = 0; it < 6; ++it) {
      int cc = tid + it * 256;           // 1536 chunks: A 512 + B 1024
      int isB = cc >= 512;
      int c3 = isB ? (cc - 512) : cc;
      int row = c3 >> 3, kb = (c3 & 7) << 4;
      const unsigned short* base = isB ? (B + (size_t)(n0 + row) * K + kt)
                                       : (A + (size_t)(m0 + row) * K + kt);
      const char* src = (const char*)base + (kb ^ ((row & 7) << 4));
      char* dstl = (char*)(isB ? Bs[b] : As[b]) + c3 * 16;
      gload16(src, dstl);
    }
  };

  stage(0, 0);
  asm volatile("s_waitcnt vmcnt(0)" ::: "memory");
  __syncthreads();
  int buf = 0;

  for (int kt = 0; kt < K; kt += 64) {
    if (kt + 64 < K) stage(kt + 64, buf ^ 1);
#pragma unroll
    for (int ks = 0; ks < 2; ++ks) {
      bf16x8 af[2], bfr[4];
#pragma unroll
      for (int i = 0; i < 2; ++i) {
        int row = wm + i * 16 + cl;
        int kb = ((g << 4) + (ks << 6)) ^ ((row & 7) << 4);
        af[i] = *(const bf16x8*)((const char*)As[buf] + row * 128 + kb);
      }
#pragma unroll
      for (int j = 0; j < 4; ++j) {
        int row = wn + j * 16 + cl;
        int kb = ((g << 4) + (ks << 6)) ^ ((row & 7) << 4);
        bfr[j] = *(const bf16x8*)((const char*)Bs[buf] + row * 128 + kb);
      }
#pragma unroll
      for (int i = 0; i < 2; ++i)
#pragma unroll
        for (int j = 0; j < 4; ++j)
          acc[i][j] = __builtin_amdgcn_mfma_f32_16x16x32_bf16(af[i], bfr[j], acc[i][j], 0, 0, 0);
    }
    asm volatile("s_waitcnt vmcnt(0)" ::: "memory");
    __syncthreads();
    buf ^= 1;
  }

  if (ROPE && n0 >= 2560) {
    // V region: write transposed to VT[d][l], 4 consecutive l per thread (8B stores)
#pragma unroll
    for (int i = 0; i < 2; ++i)
#pragma unroll
      for (int j = 0; j < 4; ++j) {
        int d = n0 - 2560 + wn + j * 16 + cl;
        int l0r = m0 + wm + i * 16 + (g << 2);
        ushort4 o;
        o.x = f2bf(acc[i][j][0]); o.y = f2bf(acc[i][j][1]);
        o.z = f2bf(acc[i][j][2]); o.w = f2bf(acc[i][j][3]);
        *(ushort4*)(vtout + (size_t)d * 2048 + l0r) = o;
      }
    return;
  }

  if (ROPE) {  // Q (scaled by attn_scale*0.125*log2e) or K: half-split RoPE in fp32
    float s0v = scale_p[0] * 0.125f * 1.4426950408889634f;
    float sc = (n0 < 2048) ? s0v : 1.0f;
    float invf[2];
#pragma unroll
    for (int j = 0; j < 2; ++j)
      invf[j] = __expf(-(float)(j * 16 + cl) * 0.2878231366242557f);
#pragma unroll
    for (int i = 0; i < 2; ++i)
#pragma unroll
      for (int r = 0; r < 4; ++r) {
        float pos = (float)(m0 + wm + i * 16 + (g << 2) + r);
#pragma unroll
        for (int j = 0; j < 2; ++j) {
          float ang = pos * invf[j];
          float sn, cs;
          __sincosf(ang, &sn, &cs);
          float t1 = acc[i][j][r], t2 = acc[i][j + 2][r];
          acc[i][j][r] = (t1 * cs - t2 * sn) * sc;
          acc[i][j + 2][r] = (t1 * sn + t2 * cs) * sc;
        }
      }
  }

#pragma unroll
  for (int i = 0; i < 2; ++i)
#pragma unroll
    for (int j = 0; j < 4; ++j)
#pragma unroll
      for (int r = 0; r < 4; ++r) {
        int row = m0 + wm + i * 16 + (g << 2) + r;
        int col = n0 + wn + j * 16 + cl;
        float v = acc[i][j][r];
        if (OUTF32)
          ((float*)Cout)[(size_t)row * N + col] = v;
        else
          ((unsigned short*)Cout)[(size_t)row * N + col] = f2bf(v);
      }
}

// ---------------- Flash attention: R14 engine, unroll-by-2 ping-pong score buffers -------
// Block = (head h, 64 q rows), 4 waves x 16 q. Max-free exp2 softmax (zero cross-lane per
// tile). BODY(i, cur, nxt): stage(i+2)/(i+1) -> QK(i+1)->nxt -> SM+PV on cur -> vmcnt+bar.
// Ping-pong svA/svB (static identities) removes the 16 v_mov copies per iteration.
__global__ __launch_bounds__(256) void k_attn(const unsigned short* __restrict__ qkv,
                                              const unsigned short* __restrict__ vt,
                                              unsigned short* __restrict__ ao) {
  __shared__ unsigned short Ks[2][64 * 64];
  __shared__ unsigned short Vs[2][64 * 64];
  __shared__ unsigned short Ps[4 * 16 * 64];
  const int tid = threadIdx.x;
  const int w = tid >> 6, lane = tid & 63;
  const int g = lane >> 4, cl = lane & 15;
  const int h = blockIdx.x & 31;
  const int qb = 31 - (blockIdx.x >> 5);
  const int q0 = qb << 6;
  const int hk = h >> 2;
  const int qg = q0 + w * 16 + cl;

  const unsigned short* qptr = qkv + (size_t)qg * 3072 + h * 64 + g * 8;
  bf16x8 qf0 = *(const bf16x8*)qptr;
  bf16x8 qf1 = *(const bf16x8*)(qptr + 32);

  float l_lane = 0.0f;
  f32x4 acc[4] = {};

  char* myP = (char*)Ps + w * 2048;

  const int row0 = tid >> 3, row1 = (tid + 256) >> 3;
  const int kb0 = (tid & 7) << 4, kb1 = ((tid + 256) & 7) << 4;
  const char* kSrc0 = (const char*)(qkv + 2048 + hk * 64 + (size_t)row0 * 3072) + (kb0 ^ ((row0 & 7) << 4));
  const char* kSrc1 = (const char*)(qkv + 2048 + hk * 64 + (size_t)row1 * 3072) + (kb1 ^ ((row1 & 7) << 4));
  const char* vSrc0 = (const char*)(vt + (size_t)hk * 64 * 2048 + (size_t)row0 * 2048) + (kb0 ^ ((row0 & 7) << 4));
  const char* vSrc1 = (const char*)(vt + (size_t)hk * 64 * 2048 + (size_t)row1 * 2048) + (kb1 ^ ((row1 & 7) << 4));

  auto stageK = [&](int ck, int b) {
    size_t off = (size_t)ck * 393216;  // 64 rows * 3072 elems * 2B
    gload16(kSrc0 + off, (char*)Ks[b] + tid * 16);
    gload16(kSrc1 + off, (char*)Ks[b] + (tid + 256) * 16);
  };
  auto stageV = [&](int ck, int b) {
    size_t off = (size_t)ck * 128;     // 64 elems * 2B along the row
    gload16(vSrc0 + off, (char*)Vs[b] + tid * 16);
    gload16(vSrc1 + off, (char*)Vs[b] + (tid + 256) * 16);
  };

  stageK(0, 0); stageV(0, 0);
  if (qb >= 1) stageK(1, 1);
  asm volatile("s_waitcnt vmcnt(0)" ::: "memory");
  __syncthreads();

  float svA[4][4], svB[4][4];
  {
    const char* Kc = (const char*)Ks[0];
    __builtin_amdgcn_s_setprio(1);
#pragma unroll
    for (int t = 0; t < 4; ++t) {
      f32x4 stv = {};
#pragma unroll
      for (int ks = 0; ks < 2; ++ks) {
        int row = t * 16 + cl;
        int kb = ((g << 4) + (ks << 6)) ^ ((row & 7) << 4);
        bf16x8 kf = *(const bf16x8*)(Kc + row * 128 + kb);
        stv = __builtin_amdgcn_mfma_f32_16x16x32_bf16(kf, ks ? qf1 : qf0, stv, 0, 0, 0);
      }
#pragma unroll
      for (int r = 0; r < 4; ++r) svA[t][r] = stv[r];
    }
    __builtin_amdgcn_s_setprio(0);
  }
  __syncthreads();  // all waves done with Ks[0] before iter-0 stages K(2) into it

#define ATTN_BODY(I, CUR, NXT)                                                         \
  {                                                                                    \
    const int i_ = (I);                                                                \
    if (i_ + 2 <= qb) stageK(i_ + 2, i_ & 1);                                          \
    if (i_ + 1 <= qb) stageV(i_ + 1, (i_ + 1) & 1);                                    \
    if (i_ < qb) {                                                                     \
      const char* Kc = (const char*)Ks[(i_ + 1) & 1];                                  \
      __builtin_amdgcn_s_setprio(1);                                                   \
      _Pragma("unroll")                                                                \
      for (int t = 0; t < 4; ++t) {                                                    \
        f32x4 stv = {};                                                                \
        _Pragma("unroll")                                                              \
        for (int ks = 0; ks < 2; ++ks) {                                               \
          int row = t * 16 + cl;                                                       \
          int kb = ((g << 4) + (ks << 6)) ^ ((row & 7) << 4);                          \
          bf16x8 kf = *(const bf16x8*)(Kc + row * 128 + kb);                           \
          stv = __builtin_amdgcn_mfma_f32_16x16x32_bf16(kf, ks ? qf1 : qf0, stv, 0, 0, 0); \
        }                                                                              \
        _Pragma("unroll")                                                              \
        for (int r = 0; r < 4; ++r) NXT[t][r] = stv[r];                                \
      }                                                                                \
      __builtin_amdgcn_s_setprio(0);                                                   \
    }                                                                                  \
    if (i_ == qb) {                                                                    \
      const int kv0 = i_ << 6;                                                         \
      _Pragma("unroll")                                                                \
      for (int t = 0; t < 4; ++t)                                                      \
        _Pragma("unroll")                                                              \
        for (int r = 0; r < 4; ++r) {                                                  \
          int kvg = kv0 + t * 16 + (g << 2) + r;                                       \
          if (kvg > qg) CUR[t][r] = -1e9f;                                             \
        }                                                                              \
    }                                                                                  \
    float ps[4];                                                                       \
    _Pragma("unroll")                                                                  \
    for (int t = 0; t < 4; ++t) {                                                      \
      float e0 = __builtin_exp2f(CUR[t][0]);                                           \
      float e1 = __builtin_exp2f(CUR[t][1]);                                           \
      float e2 = __builtin_exp2f(CUR[t][2]);                                           \
      float e3 = __builtin_exp2f(CUR[t][3]);                                           \
      ps[t] = (e0 + e1) + (e2 + e3);                                                   \
      uint32_t d0, d1;                                                                 \
      asm("v_cvt_pk_bf16_f32 %0, %1, %2" : "=v"(d0) : "v"(e0), "v"(e1));               \
      asm("v_cvt_pk_bf16_f32 %0, %1, %2" : "=v"(d1) : "v"(e2), "v"(e3));               \
      uint2 dd; dd.x = d0; dd.y = d1;                                                  \
      int kb = ((t << 5) + (g << 3)) ^ ((cl & 7) << 4);                                \
      *(uint2*)(myP + cl * 128 + kb) = dd;                                             \
    }                                                                                  \
    l_lane += (ps[0] + ps[1]) + (ps[2] + ps[3]);                                       \
    {                                                                                  \
      const char* Vc = (const char*)Vs[i_ & 1];                                        \
      __builtin_amdgcn_s_setprio(1);                                                   \
      _Pragma("unroll")                                                                \
      for (int ks = 0; ks < 2; ++ks) {                                                 \
        int kbp = ((g << 4) + (ks << 6)) ^ ((cl & 7) << 4);                            \
        bf16x8 pf = *(const bf16x8*)(myP + cl * 128 + kbp);                            \
        _Pragma("unroll")                                                              \
        for (int t = 0; t < 4; ++t) {                                                  \
          int row = t * 16 + cl;                                                       \
          int kbv = ((g << 4) + (ks << 6)) ^ ((row & 7) << 4);                         \
          bf16x8 vf = *(const bf16x8*)(Vc + row * 128 + kbv);                          \
          acc[t] = __builtin_amdgcn_mfma_f32_16x16x32_bf16(pf, vf, acc[t], 0, 0, 0);   \
        }                                                                              \
      }                                                                                \
      __builtin_amdgcn_s_setprio(0);                                                   \
    }                                                                                  \
    if (i_ < qb) {                                                                     \
      asm volatile("s_waitcnt vmcnt(0)" ::: "memory");                                 \
      __syncthreads();                                                                 \
    }                                                                                  \
  }

  for (int i = 0; i <= qb; i += 2) {
    ATTN_BODY(i, svA, svB);
    if (i + 1 <= qb) ATTN_BODY(i + 1, svB, svA);
  }
#undef ATTN_BODY

  l_lane += __shfl_xor(l_lane, 16);
  l_lane += __shfl_xor(l_lane, 32);
  float li[4];
#pragma unroll
  for (int r = 0; r < 4; ++r) li[r] = 1.0f / __shfl(l_lane, (g << 2) + r);
#pragma unroll
  for (int t = 0; t < 4; ++t)
#pragma unroll
    for (int r = 0; r < 4; ++r) {
      int row = q0 + w * 16 + (g << 2) + r;
      int col = h * 64 + t * 16 + cl;
      ao[(size_t)row * 2048 + col] = f2bf(acc[t][r] * li[r]);
    }
}

extern "C" void kernel_launch(void* const* d_in, const int* in_sizes, int n_in,
                              void* d_out, int out_size, void* d_ws, size_t ws_size,
                              hipStream_t stream) {
  (void)in_sizes; (void)n_in; (void)out_size; (void)ws_size;
  const float* x  = (const float*)d_in[0];
  const float* sc = (const float*)d_in[1];
  // d_in[2] = mask (causal, applied analytically)
  const float* Wq = (const float*)d_in[3];
  const float* Wk = (const float*)d_in[4];
  const float* Wv = (const float*)d_in[5];
  const float* Wo = (const float*)d_in[6];
  float* out = (float*)d_out;
  char* ws = (char*)d_ws;
  unsigned short* xb   = (unsigned short*)(ws);              // 8 MB
  unsigned short* Wcat = (unsigned short*)(ws + 8388608);    // 12 MB  [3072][2048]
  unsigned short* Wob  = (unsigned short*)(ws + 20971520);   // 8 MB
  unsigned short* QKV  = (unsigned short*)(ws + 29360128);   // 12 MB  [2048][3072] (V third unused)
  unsigned short* VT   = (unsigned short*)(ws + 41943040);   // 2 MB   [8][64][2048]
  unsigned short* AO   = (unsigned short*)(ws + 44040192);   // 8 MB   [2048][2048]

  k_cvt_all<<<14336, 256, 0, stream>>>(x, Wq, Wk, Wv, Wo, xb, Wcat, Wob);
  k_gemm<0, 1><<<768, 256, 0, stream>>>(xb, Wcat, QKV, 2048, 3072, 2048, sc, VT);  // RoPE + V->VT
  k_attn<<<1024, 256, 0, stream>>>(QKV, VT, AO);
  k_gemm<1, 0><<<512, 256, 0, stream>>>(AO, Wob, out, 2048, 2048, 2048, nullptr, nullptr);
}

// Round 19
// 115.787 us; speedup vs baseline: 1.1191x; 1.0028x over previous
//
#include <hip/hip_runtime.h>
#include <stdint.h>

typedef short bf16x8 __attribute__((ext_vector_type(8)));
typedef float f32x4 __attribute__((ext_vector_type(4)));

__device__ __forceinline__ unsigned short f2bf(float f) {
  uint32_t u = __float_as_uint(f);
  u = (u + 0x7FFFu + ((u >> 16) & 1u)) >> 16;
  return (unsigned short)u;
}

__device__ __forceinline__ void gload16(const void* g, void* lds) {
  const __attribute__((address_space(1))) char* gp =
      (const __attribute__((address_space(1))) char*)(uintptr_t)g;
  __attribute__((address_space(3))) char* sp =
      (__attribute__((address_space(3))) char*)(uint32_t)(uintptr_t)lds;
  __builtin_amdgcn_global_load_lds(gp, sp, 16, 0, 0);
}

// ---------------- fused fp32 -> bf16 converts (all 5 tensors, one dispatch) ----------------
__global__ void k_cvt_all(const float* __restrict__ x, const float* __restrict__ Wq,
                          const float* __restrict__ Wk, const float* __restrict__ Wv,
                          const float* __restrict__ Wo, unsigned short* __restrict__ xb,
                          unsigned short* __restrict__ Wcat, unsigned short* __restrict__ Wob) {
  int b = blockIdx.x;
  const float* src;
  unsigned short* dst;
  int off;
  if (b < 4096)       { src = x;  dst = xb;                  off = b; }
  else if (b < 8192)  { src = Wq; dst = Wcat;                off = b - 4096; }
  else if (b < 9216)  { src = Wk; dst = Wcat + 2048 * 2048;  off = b - 8192; }
  else if (b < 10240) { src = Wv; dst = Wcat + 2560 * 2048;  off = b - 9216; }
  else                { src = Wo; dst = Wob;                  off = b - 10240; }
  int i = off * 256 + threadIdx.x;
  float4 v = ((const float4*)src)[i];
  ushort4 o;
  o.x = f2bf(v.x); o.y = f2bf(v.y); o.z = f2bf(v.z); o.w = f2bf(v.w);
  ((ushort4*)dst)[i] = o;
}

// ---------------- bf16 GEMM, 64x128 tile (3 blocks/CU), dbuf: C = A B^T ----------------
// ROPE=1 (gemm0): fp32 RoPE epilogue on Q (scaled, exp2-domain fold) and K; V region
// (n0>=2560, tile-uniform at BN=128) written TRANSPOSED to vtout[d][l] (k_vt fused).
template <int OUTF32, int ROPE>
__global__ __launch_bounds__(256) void k_gemm(const unsigned short* __restrict__ A,
                                              const unsigned short* __restrict__ B,
                                              void* __restrict__ Cout,
                                              int M, int N, int K,
                                              const float* __restrict__ scale_p,
                                              unsigned short* __restrict__ vtout) {
  __shared__ unsigned short As[2][64 * 64];    // 8KB each
  __shared__ unsigned short Bs[2][128 * 64];   // 16KB each
  const int tid = threadIdx.x;
  const int w = tid >> 6, lane = tid & 63;
  const int g = lane >> 4, cl = lane & 15;
  const int nTn = N >> 7;
  const int per = gridDim.x >> 3;
  const int bid = (blockIdx.x & 7) * per + (blockIdx.x >> 3);
  const int tm = bid / nTn, tn = bid % nTn;
  const int m0 = tm << 6, n0 = tn << 7;
  const int wm = (w >> 1) << 5, wn = (w & 1) << 6;  // wave: 32 rows x 64 cols
  f32x4 acc[2][4] = {};

  auto stage = [&](int kt, int b) {
#pragma unroll
    for (int it = 0; it < 6; ++it) {
      int cc = tid + it * 256;           // 1536 chunks: A 512 + B 1024
      int isB = cc >= 512;
      int c3 = isB ? (cc - 512) : cc;
      int row = c3 >> 3, kb = (c3 & 7) << 4;
      const unsigned short* base = isB ? (B + (size_t)(n0 + row) * K + kt)
                                       : (A + (size_t)(m0 + row) * K + kt);
      const char* src = (const char*)base + (kb ^ ((row & 7) << 4));
      char* dstl = (char*)(isB ? Bs[b] : As[b]) + c3 * 16;
      gload16(src, dstl);
    }
  };

  stage(0, 0);
  asm volatile("s_waitcnt vmcnt(0)" ::: "memory");
  __syncthreads();
  int buf = 0;

  for (int kt = 0; kt < K; kt += 64) {
    if (kt + 64 < K) stage(kt + 64, buf ^ 1);
#pragma unroll
    for (int ks = 0; ks < 2; ++ks) {
      bf16x8 af[2], bfr[4];
#pragma unroll
      for (int i = 0; i < 2; ++i) {
        int row = wm + i * 16 + cl;
        int kb = ((g << 4) + (ks << 6)) ^ ((row & 7) << 4);
        af[i] = *(const bf16x8*)((const char*)As[buf] + row * 128 + kb);
      }
#pragma unroll
      for (int j = 0; j < 4; ++j) {
        int row = wn + j * 16 + cl;
        int kb = ((g << 4) + (ks << 6)) ^ ((row & 7) << 4);
        bfr[j] = *(const bf16x8*)((const char*)Bs[buf] + row * 128 + kb);
      }
#pragma unroll
      for (int i = 0; i < 2; ++i)
#pragma unroll
        for (int j = 0; j < 4; ++j)
          acc[i][j] = __builtin_amdgcn_mfma_f32_16x16x32_bf16(af[i], bfr[j], acc[i][j], 0, 0, 0);
    }
    asm volatile("s_waitcnt vmcnt(0)" ::: "memory");
    __syncthreads();
    buf ^= 1;
  }

  if (ROPE && n0 >= 2560) {
    // V region: write transposed to VT[d][l], 4 consecutive l per thread (8B stores)
#pragma unroll
    for (int i = 0; i < 2; ++i)
#pragma unroll
      for (int j = 0; j < 4; ++j) {
        int d = n0 - 2560 + wn + j * 16 + cl;
        int l0r = m0 + wm + i * 16 + (g << 2);
        ushort4 o;
        o.x = f2bf(acc[i][j][0]); o.y = f2bf(acc[i][j][1]);
        o.z = f2bf(acc[i][j][2]); o.w = f2bf(acc[i][j][3]);
        *(ushort4*)(vtout + (size_t)d * 2048 + l0r) = o;
      }
    return;
  }

  if (ROPE) {  // Q (scaled by attn_scale*0.125*log2e) or K: half-split RoPE in fp32
    float s0v = scale_p[0] * 0.125f * 1.4426950408889634f;
    float sc = (n0 < 2048) ? s0v : 1.0f;
    float invf[2];
#pragma unroll
    for (int j = 0; j < 2; ++j)
      invf[j] = __expf(-(float)(j * 16 + cl) * 0.2878231366242557f);
#pragma unroll
    for (int i = 0; i < 2; ++i)
#pragma unroll
      for (int r = 0; r < 4; ++r) {
        float pos = (float)(m0 + wm + i * 16 + (g << 2) + r);
#pragma unroll
        for (int j = 0; j < 2; ++j) {
          float ang = pos * invf[j];
          float sn, cs;
          __sincosf(ang, &sn, &cs);
          float t1 = acc[i][j][r], t2 = acc[i][j + 2][r];
          acc[i][j][r] = (t1 * cs - t2 * sn) * sc;
          acc[i][j + 2][r] = (t1 * sn + t2 * cs) * sc;
        }
      }
  }

#pragma unroll
  for (int i = 0; i < 2; ++i)
#pragma unroll
    for (int j = 0; j < 4; ++j)
#pragma unroll
      for (int r = 0; r < 4; ++r) {
        int row = m0 + wm + i * 16 + (g << 2) + r;
        int col = n0 + wn + j * 16 + cl;
        float v = acc[i][j][r];
        if (OUTF32)
          ((float*)Cout)[(size_t)row * N + col] = v;
        else
          ((unsigned short*)Cout)[(size_t)row * N + col] = f2bf(v);
      }
}

// ---------------- Flash attention: R14 engine + l-via-MFMA + hoisted LDS offsets --------
// Block = (head h, 64 q rows), 4 waves x 16 q. Max-free exp2 softmax. l computed by an
// extra MFMA with all-ones B (matrix pipe, ~idle) instead of a 16-add VALU tree; its D
// layout (row=4g+r) lands l[q] exactly where the epilogue needs it (zero shuffles).
// All loop-invariant LDS byte-offsets hoisted to per-thread constants.
__global__ __launch_bounds__(256) void k_attn(const unsigned short* __restrict__ qkv,
                                              const unsigned short* __restrict__ vt,
                                              unsigned short* __restrict__ ao) {
  __shared__ unsigned short Ks[2][64 * 64];
  __shared__ unsigned short Vs[2][64 * 64];
  __shared__ unsigned short Ps[4 * 16 * 64];
  const int tid = threadIdx.x;
  const int w = tid >> 6, lane = tid & 63;
  const int g = lane >> 4, cl = lane & 15;
  const int h = blockIdx.x & 31;
  const int qb = 31 - (blockIdx.x >> 5);
  const int q0 = qb << 6;
  const int hk = h >> 2;
  const int qg = q0 + w * 16 + cl;

  const unsigned short* qptr = qkv + (size_t)qg * 3072 + h * 64 + g * 8;
  bf16x8 qf0 = *(const bf16x8*)qptr;
  bf16x8 qf1 = *(const bf16x8*)(qptr + 32);

  const short ob = (short)0x3F80;  // bf16 1.0
  const bf16x8 onesf = {ob, ob, ob, ob, ob, ob, ob, ob};

  f32x4 acc[4] = {};
  f32x4 acc_l = {};

  char* myP = (char*)Ps + w * 2048;

  // ---- hoisted loop-invariant LDS byte offsets ----
  int kvOff[2][4];   // K/V ds_read offsets (128B rows, same formula both)
#pragma unroll
  for (int ks = 0; ks < 2; ++ks)
#pragma unroll
    for (int t = 0; t < 4; ++t) {
      int row = t * 16 + cl;
      kvOff[ks][t] = row * 128 + (((g << 4) + (ks << 6)) ^ ((row & 7) << 4));
    }
  int pwOff[4];      // P write offsets
#pragma unroll
  for (int t = 0; t < 4; ++t)
    pwOff[t] = cl * 128 + (((t << 5) + (g << 3)) ^ ((cl & 7) << 4));
  int prOff[2];      // P read offsets
#pragma unroll
  for (int ks = 0; ks < 2; ++ks)
    prOff[ks] = cl * 128 + (((g << 4) + (ks << 6)) ^ ((cl & 7) << 4));

  const int row0 = tid >> 3, row1 = (tid + 256) >> 3;
  const int kb0 = (tid & 7) << 4, kb1 = ((tid + 256) & 7) << 4;
  const char* kSrc0 = (const char*)(qkv + 2048 + hk * 64 + (size_t)row0 * 3072) + (kb0 ^ ((row0 & 7) << 4));
  const char* kSrc1 = (const char*)(qkv + 2048 + hk * 64 + (size_t)row1 * 3072) + (kb1 ^ ((row1 & 7) << 4));
  const char* vSrc0 = (const char*)(vt + (size_t)hk * 64 * 2048 + (size_t)row0 * 2048) + (kb0 ^ ((row0 & 7) << 4));
  const char* vSrc1 = (const char*)(vt + (size_t)hk * 64 * 2048 + (size_t)row1 * 2048) + (kb1 ^ ((row1 & 7) << 4));

  auto stageK = [&](int ck, int b) {
    size_t off = (size_t)ck * 393216;  // 64 rows * 3072 elems * 2B
    gload16(kSrc0 + off, (char*)Ks[b] + tid * 16);
    gload16(kSrc1 + off, (char*)Ks[b] + (tid + 256) * 16);
  };
  auto stageV = [&](int ck, int b) {
    size_t off = (size_t)ck * 128;     // 64 elems * 2B along the row
    gload16(vSrc0 + off, (char*)Vs[b] + tid * 16);
    gload16(vSrc1 + off, (char*)Vs[b] + (tid + 256) * 16);
  };

  stageK(0, 0); stageV(0, 0);
  if (qb >= 1) stageK(1, 1);
  asm volatile("s_waitcnt vmcnt(0)" ::: "memory");
  __syncthreads();

  float svA[4][4], svB[4][4];
  {
    const char* Kc = (const char*)Ks[0];
    __builtin_amdgcn_s_setprio(1);
#pragma unroll
    for (int t = 0; t < 4; ++t) {
      f32x4 stv = {};
#pragma unroll
      for (int ks = 0; ks < 2; ++ks) {
        bf16x8 kf = *(const bf16x8*)(Kc + kvOff[ks][t]);
        stv = __builtin_amdgcn_mfma_f32_16x16x32_bf16(kf, ks ? qf1 : qf0, stv, 0, 0, 0);
      }
#pragma unroll
      for (int r = 0; r < 4; ++r) svA[t][r] = stv[r];
    }
    __builtin_amdgcn_s_setprio(0);
  }
  __syncthreads();  // all waves done with Ks[0] before iter-0 stages K(2) into it

#define ATTN_BODY(I, CUR, NXT)                                                         \
  {                                                                                    \
    const int i_ = (I);                                                                \
    if (i_ + 2 <= qb) stageK(i_ + 2, i_ & 1);                                          \
    if (i_ + 1 <= qb) stageV(i_ + 1, (i_ + 1) & 1);                                    \
    if (i_ < qb) {                                                                     \
      const char* Kc = (const char*)Ks[(i_ + 1) & 1];                                  \
      __builtin_amdgcn_s_setprio(1);                                                   \
      _Pragma("unroll")                                                                \
      for (int t = 0; t < 4; ++t) {                                                    \
        f32x4 stv = {};                                                                \
        _Pragma("unroll")                                                              \
        for (int ks = 0; ks < 2; ++ks) {                                               \
          bf16x8 kf = *(const bf16x8*)(Kc + kvOff[ks][t]);                             \
          stv = __builtin_amdgcn_mfma_f32_16x16x32_bf16(kf, ks ? qf1 : qf0, stv, 0, 0, 0); \
        }                                                                              \
        _Pragma("unroll")                                                              \
        for (int r = 0; r < 4; ++r) NXT[t][r] = stv[r];                                \
      }                                                                                \
      __builtin_amdgcn_s_setprio(0);                                                   \
    }                                                                                  \
    if (i_ == qb) {                                                                    \
      const int kv0 = i_ << 6;                                                         \
      _Pragma("unroll")                                                                \
      for (int t = 0; t < 4; ++t)                                                      \
        _Pragma("unroll")                                                              \
        for (int r = 0; r < 4; ++r) {                                                  \
          int kvg = kv0 + t * 16 + (g << 2) + r;                                       \
          if (kvg > qg) CUR[t][r] = -1e9f;                                             \
        }                                                                              \
    }                                                                                  \
    _Pragma("unroll")                                                                  \
    for (int t = 0; t < 4; ++t) {                                                      \
      float e0 = __builtin_exp2f(CUR[t][0]);                                           \
      float e1 = __builtin_exp2f(CUR[t][1]);                                           \
      float e2 = __builtin_exp2f(CUR[t][2]);                                           \
      float e3 = __builtin_exp2f(CUR[t][3]);                                           \
      uint32_t d0, d1;                                                                 \
      asm("v_cvt_pk_bf16_f32 %0, %1, %2" : "=v"(d0) : "v"(e0), "v"(e1));               \
      asm("v_cvt_pk_bf16_f32 %0, %1, %2" : "=v"(d1) : "v"(e2), "v"(e3));               \
      uint2 dd; dd.x = d0; dd.y = d1;                                                  \
      *(uint2*)(myP + pwOff[t]) = dd;                                                  \
    }                                                                                  \
    {                                                                                  \
      const char* Vc = (const char*)Vs[i_ & 1];                                        \
      __builtin_amdgcn_s_setprio(1);                                                   \
      _Pragma("unroll")                                                                \
      for (int ks = 0; ks < 2; ++ks) {                                                 \
        bf16x8 pf = *(const bf16x8*)(myP + prOff[ks]);                                 \
        acc_l = __builtin_amdgcn_mfma_f32_16x16x32_bf16(pf, onesf, acc_l, 0, 0, 0);    \
        _Pragma("unroll")                                                              \
        for (int t = 0; t < 4; ++t) {                                                  \
          bf16x8 vf = *(const bf16x8*)(Vc + kvOff[ks][t]);                             \
          acc[t] = __builtin_amdgcn_mfma_f32_16x16x32_bf16(pf, vf, acc[t], 0, 0, 0);   \
        }                                                                              \
      }                                                                                \
      __builtin_amdgcn_s_setprio(0);                                                   \
    }                                                                                  \
    if (i_ < qb) {                                                                     \
      asm volatile("s_waitcnt vmcnt(0)" ::: "memory");                                 \
      __syncthreads();                                                                 \
    }                                                                                  \
  }

  for (int i = 0; i <= qb; i += 2) {
    ATTN_BODY(i, svA, svB);
    if (i + 1 <= qb) ATTN_BODY(i + 1, svB, svA);
  }
#undef ATTN_BODY

  // acc_l[r] = l for q-row (4g+r) — same D layout as acc: zero shuffles needed.
  float li[4];
#pragma unroll
  for (int r = 0; r < 4; ++r) li[r] = 1.0f / acc_l[r];
#pragma unroll
  for (int t = 0; t < 4; ++t)
#pragma unroll
    for (int r = 0; r < 4; ++r) {
      int row = q0 + w * 16 + (g << 2) + r;
      int col = h * 64 + t * 16 + cl;
      ao[(size_t)row * 2048 + col] = f2bf(acc[t][r] * li[r]);
    }
}

extern "C" void kernel_launch(void* const* d_in, const int* in_sizes, int n_in,
                              void* d_out, int out_size, void* d_ws, size_t ws_size,
                              hipStream_t stream) {
  (void)in_sizes; (void)n_in; (void)out_size; (void)ws_size;
  const float* x  = (const float*)d_in[0];
  const float* sc = (const float*)d_in[1];
  // d_in[2] = mask (causal, applied analytically)
  const float* Wq = (const float*)d_in[3];
  const float* Wk = (const float*)d_in[4];
  const float* Wv = (const float*)d_in[5];
  const float* Wo = (const float*)d_in[6];
  float* out = (float*)d_out;
  char* ws = (char*)d_ws;
  unsigned short* xb   = (unsigned short*)(ws);              // 8 MB
  unsigned short* Wcat = (unsigned short*)(ws + 8388608);    // 12 MB  [3072][2048]
  unsigned short* Wob  = (unsigned short*)(ws + 20971520);   // 8 MB
  unsigned short* QKV  = (unsigned short*)(ws + 29360128);   // 12 MB  [2048][3072] (V third unused)
  unsigned short* VT   = (unsigned short*)(ws + 41943040);   // 2 MB   [8][64][2048]
  unsigned short* AO   = (unsigned short*)(ws + 44040192);   // 8 MB   [2048][2048]

  k_cvt_all<<<14336, 256, 0, stream>>>(x, Wq, Wk, Wv, Wo, xb, Wcat, Wob);
  k_gemm<0, 1><<<768, 256, 0, stream>>>(xb, Wcat, QKV, 2048, 3072, 2048, sc, VT);  // RoPE + V->VT
  k_attn<<<1024, 256, 0, stream>>>(QKV, VT, AO);
  k_gemm<1, 0><<<512, 256, 0, stream>>>(AO, Wob, out, 2048, 2048, 2048, nullptr, nullptr);
}